// Round 3
// baseline (103.019 us; speedup 1.0000x reference)
//
#include <hip/hip_runtime.h>

#define N       8192   // 8*32*32  (DEPTH=8, LENGTH=32, WIDTH=32)
#define NCLS    8
#define NBUCK   256    // power of two
#define ROWS_PB 4      // one wave (64 lanes) per row, 4 rows per 256-thread block
#define GRID    (N / ROWS_PB)   // 2048 blocks

// Fused kernel: one WAVE per row i. Lanes cover the exact significant
// neighborhood: y in [yi-3,yi+3] (7 rows, clamped-shifted window) x
// z in [zi-4,zi+4] (9 cols). Dropped terms have weight <= exp(-25) ~ 1e-11;
// every computed term is exact. x-loop of 7 (clamped window) fully unrolled.
// Per-row 9 partial sums reduce across the wave; lane 0 atomically adds the
// P-weighted contributions into one of NBUCK buckets. The last block to
// finish folds the buckets into the scalar loss (last-block-done pattern).
__global__ __launch_bounds__(256) void sncut_fused(const float* __restrict__ f,
                                                   const float* __restrict__ P,
                                                   float* __restrict__ buckets,
                                                   int* __restrict__ counter,
                                                   float* __restrict__ out)
{
    const int tid  = threadIdx.x;
    const int lane = tid & 63;
    const int wave = tid >> 6;
    const int i    = blockIdx.x * ROWS_PB + wave;

    const int zi = i & 31, yi = (i >> 5) & 31, xi = i >> 10;
    const float fi = f[i];

    float v0 = 0.f, v1 = 0.f, v2 = 0.f, v3 = 0.f;
    float v4 = 0.f, v5 = 0.f, v6 = 0.f, v7 = 0.f;
    float vr = 0.f;

    if (lane < 63) {
        const int oy = lane / 9, oz = lane - oy * 9;   // 7 x 9 = 63 lanes

        int y0 = yi - 3; y0 = y0 < 0 ? 0 : (y0 > 25 ? 25 : y0);  // window in [0,31]
        int z0 = zi - 4; z0 = z0 < 0 ? 0 : (z0 > 23 ? 23 : z0);
        int x0 = xi - 3; x0 = x0 < 0 ? 0 : (x0 > 1 ? 1 : x0);    // 7 x's in [0,7]

        const int yj = y0 + oy, zj = z0 + oz;
        const int dy = yi - yj, dz = zi - zj;
        const float base = (float)(dy * dy + dz * dz);
        const int jcol = (yj << 5) + zj;

        #pragma unroll
        for (int k = 0; k < 7; ++k) {
            const int xj = x0 + k;
            const int dx = xi - xj;
            const int j  = (xj << 10) + jcol;
            const float df  = fi - f[j];
            const float arg = df * df * (1.0f / 9.0f) + (base + (float)(dx * dx));
            const float w   = __expf(-arg);
            const float4 p0 = *reinterpret_cast<const float4*>(P + (size_t)j * NCLS);
            const float4 p1 = *reinterpret_cast<const float4*>(P + (size_t)j * NCLS + 4);
            v0 += w * p0.x; v1 += w * p0.y; v2 += w * p0.z; v3 += w * p0.w;
            v4 += w * p1.x; v5 += w * p1.y; v6 += w * p1.z; v7 += w * p1.w;
            vr += w;
        }
    }

    // ---- wave reduction (result lands in lane 0)
    float vals[9] = {v0, v1, v2, v3, v4, v5, v6, v7, vr};
    #pragma unroll
    for (int v = 0; v < 9; ++v) {
        float x = vals[v];
        #pragma unroll
        for (int off = 32; off > 0; off >>= 1)
            x += __shfl_down(x, off, 64);
        vals[v] = x;
    }

    if (lane == 0) {
        const float4 p0 = *reinterpret_cast<const float4*>(P + (size_t)i * NCLS);
        const float4 p1 = *reinterpret_cast<const float4*>(P + (size_t)i * NCLS + 4);
        float* b = buckets + (i & (NBUCK - 1)) * 16;
        atomicAdd(b + 0, p0.x * vals[0]);
        atomicAdd(b + 1, p0.y * vals[1]);
        atomicAdd(b + 2, p0.z * vals[2]);
        atomicAdd(b + 3, p0.w * vals[3]);
        atomicAdd(b + 4, p1.x * vals[4]);
        atomicAdd(b + 5, p1.y * vals[5]);
        atomicAdd(b + 6, p1.z * vals[6]);
        atomicAdd(b + 7, p1.w * vals[7]);
        atomicAdd(b + 8,  p0.x * vals[8]);
        atomicAdd(b + 9,  p0.y * vals[8]);
        atomicAdd(b + 10, p0.z * vals[8]);
        atomicAdd(b + 11, p0.w * vals[8]);
        atomicAdd(b + 12, p1.x * vals[8]);
        atomicAdd(b + 13, p1.y * vals[8]);
        atomicAdd(b + 14, p1.z * vals[8]);
        atomicAdd(b + 15, p1.w * vals[8]);
    }

    // ---- last-block-done: the final arriving block folds the buckets
    __shared__ int isLast;
    __syncthreads();
    if (tid == 0) {
        __threadfence();                       // make our atomics visible
        int old = atomicAdd(counter, 1);
        isLast = (old == (int)gridDim.x - 1);
    }
    __syncthreads();
    if (!isLast) return;

    __threadfence();                           // acquire: see all blocks' atomics
    const int e = tid & 15;                    // entry 0..15
    const int g = tid >> 4;                    // group 0..15
    float s = 0.f;
    #pragma unroll
    for (int b = 0; b < NBUCK / 16; ++b) {
        s += __hip_atomic_load(&buckets[(g + b * 16) * 16 + e],
                               __ATOMIC_RELAXED, __HIP_MEMORY_SCOPE_AGENT);
    }

    __shared__ float acc[16][17];
    acc[g][e] = s;
    __syncthreads();

    __shared__ float sums[16];
    if (tid < 16) {
        float t = 0.f;
        #pragma unroll
        for (int g2 = 0; g2 < 16; ++g2) t += acc[g2][tid];
        sums[tid] = t;
    }
    __syncthreads();
    if (tid == 0) {
        float loss = (float)NCLS;
        #pragma unroll
        for (int t = 0; t < NCLS; ++t) loss -= sums[t] / sums[NCLS + t];
        out[0] = loss;
    }
}

extern "C" void kernel_launch(void* const* d_in, const int* in_sizes, int n_in,
                              void* d_out, int out_size, void* d_ws, size_t ws_size,
                              hipStream_t stream) {
    const float* f = (const float*)d_in[0];   // patch, 8192 fp32
    const float* P = (const float*)d_in[1];   // prob, 8192x8 fp32
    // d_in[2] is k==8 (compile-time constant here)

    float* buckets = (float*)d_ws;                       // NBUCK*16 floats
    int*   counter = (int*)((char*)d_ws + NBUCK * 16 * sizeof(float));

    hipMemsetAsync(d_ws, 0, NBUCK * 16 * sizeof(float) + sizeof(int), stream);
    sncut_fused<<<GRID, 256, 0, stream>>>(f, P, buckets, counter, (float*)d_out);
}

// Round 4
// 68.045 us; speedup vs baseline: 1.5140x; 1.5140x over previous
//
#include <hip/hip_runtime.h>

#define N       8192   // 8*32*32  (DEPTH=8, LENGTH=32, WIDTH=32)
#define NCLS    8
#define ROWS_PB 4                  // one wave (64 lanes) per row, 4 rows per block
#define GRID    (N / ROWS_PB)      // 2048 blocks

// One WAVE per row i. Lanes cover the exact significant neighborhood:
// y in [yi-3,yi+3] (7 rows) x z in [zi-4,zi+4] (9 cols), x in [xi-3,xi+3]
// (7, clamp-shifted windows always inside the volume). Dropped terms have
// weight <= exp(-16) ~ 1e-7; every computed term is exact (validated R2/R3:
// absmax 0.0). Each block folds its 4 rows' 16-entry contributions in LDS
// and writes ONE non-atomic partial vector -> no atomics, no fences, no
// zero-init of d_ws required.
__global__ __launch_bounds__(256) void sncut_rows(const float* __restrict__ f,
                                                  const float* __restrict__ P,
                                                  float* __restrict__ partials)
{
    const int tid  = threadIdx.x;
    const int lane = tid & 63;
    const int wave = tid >> 6;
    const int i    = blockIdx.x * ROWS_PB + wave;

    const int zi = i & 31, yi = (i >> 5) & 31, xi = i >> 10;
    const float fi = f[i];

    float v0 = 0.f, v1 = 0.f, v2 = 0.f, v3 = 0.f;
    float v4 = 0.f, v5 = 0.f, v6 = 0.f, v7 = 0.f;
    float vr = 0.f;

    if (lane < 63) {
        const int oy = lane / 9, oz = lane - oy * 9;   // 7 x 9 = 63 lanes

        int y0 = yi - 3; y0 = y0 < 0 ? 0 : (y0 > 25 ? 25 : y0);
        int z0 = zi - 4; z0 = z0 < 0 ? 0 : (z0 > 23 ? 23 : z0);
        int x0 = xi - 3; x0 = x0 < 0 ? 0 : (x0 > 1 ? 1 : x0);

        const int yj = y0 + oy, zj = z0 + oz;
        const int dy = yi - yj, dz = zi - zj;
        const float base = (float)(dy * dy + dz * dz);
        const int jcol = (yj << 5) + zj;

        #pragma unroll
        for (int k = 0; k < 7; ++k) {
            const int xj = x0 + k;
            const int dx = xi - xj;
            const int j  = (xj << 10) + jcol;
            const float df  = fi - f[j];
            const float arg = df * df * (1.0f / 9.0f) + (base + (float)(dx * dx));
            const float w   = __expf(-arg);
            const float4 p0 = *reinterpret_cast<const float4*>(P + (size_t)j * NCLS);
            const float4 p1 = *reinterpret_cast<const float4*>(P + (size_t)j * NCLS + 4);
            v0 += w * p0.x; v1 += w * p0.y; v2 += w * p0.z; v3 += w * p0.w;
            v4 += w * p1.x; v5 += w * p1.y; v6 += w * p1.z; v7 += w * p1.w;
            vr += w;
        }
    }

    // ---- wave reduction (result lands in lane 0)
    float vals[9] = {v0, v1, v2, v3, v4, v5, v6, v7, vr};
    #pragma unroll
    for (int v = 0; v < 9; ++v) {
        float x = vals[v];
        #pragma unroll
        for (int off = 32; off > 0; off >>= 1)
            x += __shfl_down(x, off, 64);
        vals[v] = x;
    }

    // ---- per-row 16-entry contribution into LDS, fold 4 waves, one store
    __shared__ float sh[ROWS_PB][16];
    if (lane == 0) {
        const float4 p0 = *reinterpret_cast<const float4*>(P + (size_t)i * NCLS);
        const float4 p1 = *reinterpret_cast<const float4*>(P + (size_t)i * NCLS + 4);
        sh[wave][0]  = p0.x * vals[0];
        sh[wave][1]  = p0.y * vals[1];
        sh[wave][2]  = p0.z * vals[2];
        sh[wave][3]  = p0.w * vals[3];
        sh[wave][4]  = p1.x * vals[4];
        sh[wave][5]  = p1.y * vals[5];
        sh[wave][6]  = p1.z * vals[6];
        sh[wave][7]  = p1.w * vals[7];
        sh[wave][8]  = p0.x * vals[8];
        sh[wave][9]  = p0.y * vals[8];
        sh[wave][10] = p0.z * vals[8];
        sh[wave][11] = p0.w * vals[8];
        sh[wave][12] = p1.x * vals[8];
        sh[wave][13] = p1.y * vals[8];
        sh[wave][14] = p1.z * vals[8];
        sh[wave][15] = p1.w * vals[8];
    }
    __syncthreads();
    if (tid < 16) {
        const float s = sh[0][tid] + sh[1][tid] + sh[2][tid] + sh[3][tid];
        partials[(size_t)blockIdx.x * 16 + tid] = s;
    }
}

// Fold 2048 x 16 partials -> 16 sums -> scalar loss. 1024 threads:
// thread (g = tid>>4 in [0,64), e = tid&15) sums 32 strided entries
// (independent loads, latency hidden), LDS combine across groups.
__global__ __launch_bounds__(1024) void sncut_final(const float* __restrict__ partials,
                                                    float* __restrict__ out)
{
    const int tid = threadIdx.x;
    const int e = tid & 15;
    const int g = tid >> 4;        // 0..63

    float s = 0.f;
    #pragma unroll
    for (int m = 0; m < GRID / 64; ++m)        // 32 iterations
        s += partials[(size_t)(g + m * 64) * 16 + e];

    __shared__ float acc[64][17];
    acc[g][e] = s;
    __syncthreads();

    __shared__ float sums[16];
    if (tid < 16) {
        float t = 0.f;
        #pragma unroll
        for (int g2 = 0; g2 < 64; ++g2) t += acc[g2][tid];
        sums[tid] = t;
    }
    __syncthreads();
    if (tid == 0) {
        float loss = (float)NCLS;
        #pragma unroll
        for (int t = 0; t < NCLS; ++t) loss -= sums[t] / sums[NCLS + t];
        out[0] = loss;
    }
}

extern "C" void kernel_launch(void* const* d_in, const int* in_sizes, int n_in,
                              void* d_out, int out_size, void* d_ws, size_t ws_size,
                              hipStream_t stream) {
    const float* f = (const float*)d_in[0];   // patch, 8192 fp32
    const float* P = (const float*)d_in[1];   // prob, 8192x8 fp32
    // d_in[2] is k==8 (compile-time constant here)

    float* partials = (float*)d_ws;           // GRID*16 floats = 128 KB, fully overwritten

    sncut_rows<<<GRID, 256, 0, stream>>>(f, P, partials);
    sncut_final<<<1, 1024, 0, stream>>>(partials, (float*)d_out);
}